// Round 14
// baseline (11.110 us; speedup 1.0000x reference)
//
#include <hip/hip_runtime.h>
#include <math.h>

// Problem constants from the reference
#define BB 32
#define NN 8
#define TT 52
#define HH 224
#define WW 224
#define PP 100    // 10x10 local grid; point p: slot A = lane p (p<64), slot B = lane p-64
#define NWAVE 16  // waves per block (1024 threads); block = one (b,n) output

__device__ __forceinline__ float rlane_f(float v, int l) {
    return __int_as_float(__builtin_amdgcn_readlane(__float_as_int(v), l));
}

__global__ __launch_bounds__(NWAVE * 64) void mapcoll_fused(
    const float* __restrict__ x,        // (B,N,T,6)
    const float* __restrict__ dmap,     // (B,H,W)
    const float* __restrict__ extent,   // (B,3)
    const float* __restrict__ rfa,      // (B,3,3)
    float* __restrict__ out)            // (B*N)
{
    const int bn   = blockIdx.x;        // 0..255
    const int b    = bn >> 3;           // NN == 8
    const int lane = threadIdx.x & 63;
    const int wvu  = __builtin_amdgcn_readfirstlane((int)(threadIdx.x >> 6));

    __shared__ float s_w[NWAVE][4][128];   // per-wave per-t dj^2*sy^2 table, idx = r*10+j
    __shared__ float s_part[NWAVE];

    // ---- per-b uniforms (scalar loads) ----
    const float lwx = extent[b * 3 + 0];
    const float lwy = extent[b * 3 + 1];
    const float inv_diag = 1.0f / sqrtf(lwx * lwx + lwy * lwy);
    const float r00 = rfa[b*9+0], r01 = rfa[b*9+1], r02 = rfa[b*9+2];
    const float r10 = rfa[b*9+3], r11 = rfa[b*9+4], r12 = rfa[b*9+5];
    const float* __restrict__ map_b = dmap + (size_t)b * (HH * WW);
    // Rigid-motion invariance: |a_p - a_q|^2 = ((i_p-i_q)*sx)^2 + ((j_p-j_q)*sy)^2
    const float sx  = lwx * (1.0f / 9.0f);
    const float sy  = lwy * (1.0f / 9.0f);

    // ---- lane-parallel prologue: lane t<52 builds fused transform uniforms ----
    // fx = p0*u00 + p1*u01 + u0c ; fy = p0*u10 + p1*u11 + u1c   (per-t uniforms)
    float u00 = 0.f, u01 = 0.f, u0c = 0.f, u10 = 0.f, u11 = 0.f, u1c = 0.f;
    if (lane < TT) {
        const int base = (bn * TT + lane) * 6;
        const float2 p2 = *reinterpret_cast<const float2*>(x + base);
        const float yw = x[base + 3];
        const float sn = __sinf(yw), cs = __cosf(yw);
        u00 = cs * r00 + sn * r01;
        u01 = cs * r01 - sn * r00;
        u0c = p2.x * r00 + p2.y * r01 + r02;
        u10 = cs * r10 + sn * r11;
        u11 = cs * r11 - sn * r10;
        u1c = p2.x * r10 + p2.y * r11 + r12;
    }

    // ---- per-lane geometry (t-invariant) ----
    const int iA = lane / 10, jA = lane - iA * 10;
    const int pB = lane + 64;
    const int iB = pB / 10,   jB = pB - iB * 10;
    const bool hasB = (lane < PP - 64);   // 36 lanes own a B point
    const float p0A = (-0.5f + (float)iA * (1.0f/9.0f)) * lwx;
    const float p1A = (-0.5f + (float)jA * (1.0f/9.0f)) * lwy;
    const float p0B = (-0.5f + (float)iB * (1.0f/9.0f)) * lwx;
    const float p1B = (-0.5f + (float)jB * (1.0f/9.0f)) * lwy;

    // scan shift constants (per-lane, t-invariant)
    const int shA  = (10 * iA) & 63;                           // into fA (iA<6)
    const int sGA  = (10 * iA - 60) < 0 ? 0 : (10 * iA - 60);  // into G (iA>=6)
    const int sGB  = ((10 * iB - 60) & 63);                    // B always via G (iB>=6)
    const int rshA = 31 - jA;                                  // brev fold shift
    const int rshB = 31 - jB;

    // di^2 tables (hoisted out of the t loop)
    float di2A[10], di2B[10];
    #pragma unroll
    for (int r = 0; r < 10; ++r) {
        const float dA = (float)(iA - r) * sx; di2A[r] = dA * dA;
        const float dB = (float)(iB - r) * sx; di2B[r] = dB * dB;
    }

    const unsigned MARK = 1u << 25;   // empty-row sentinel: d=25 -> 625*sy2 > 26.9 max

    // t distribution: waves 0..3 -> 4 t's, waves 4..15 -> 3 t's (52 total)
    const int kn = (wvu < 4) ? 4 : 3;
    const int t0 = (wvu < 4) ? (wvu * 4) : (16 + (wvu - 4) * 3);

    // ---- phase 1: transforms + rasterize + issue ALL gathers before any use ----
    float vA[4], vB[4];
    #pragma unroll
    for (int k = 0; k < 4; ++k) {
        vA[k] = 1.0f;                       // "free" for skipped slots
        vB[k] = 1.0f;
        if (k < kn) {                       // wave-uniform guard
            const int t = t0 + k;
            const float a00 = rlane_f(u00, t), a01 = rlane_f(u01, t), a0c = rlane_f(u0c, t);
            const float a10 = rlane_f(u10, t), a11 = rlane_f(u11, t), a1c = rlane_f(u1c, t);
            {
                const float fx = fmaf(p0A, a00, fmaf(p1A, a01, a0c));
                const float fy = fmaf(p0A, a10, fmaf(p1A, a11, a1c));
                int ix = (int)fx, iy = (int)fy;   // trunc cast, then clip (ref semantics)
                ix = ix < 0 ? 0 : (ix > WW - 1 ? WW - 1 : ix);
                iy = iy < 0 ? 0 : (iy > HH - 1 ? HH - 1 : iy);
                vA[k] = map_b[iy * WW + ix];
            }
            if (hasB) {
                const float fx = fmaf(p0B, a00, fmaf(p1B, a01, a0c));
                const float fy = fmaf(p0B, a10, fmaf(p1B, a11, a1c));
                int ix = (int)fx, iy = (int)fy;
                ix = ix < 0 ? 0 : (ix > WW - 1 ? WW - 1 : ix);
                iy = iy < 0 ? 0 : (iy > HH - 1 ? HH - 1 : iy);
                vB[k] = map_b[iy * WW + ix];
            }
        }
    }

    // ---- phase 2a: ballots + mask build + per-lane scans + LDS table writes ----
    int liveMask = 0;                       // wave-uniform
    #pragma unroll
    for (int k = 0; k < 4; ++k) {
        if (k < kn) {
            const int clA = (vA[k] == 0.0f) ? 1 : 0;  // offroad==1 <=> drv==0 ({0,1} map)
            const int clB = (vB[k] == 0.0f) ? 1 : 0;
            const unsigned long long cmA = __ballot(clA);
            const unsigned long long cmB = __ballot(clB);
            const int ncoll = __popcll(cmA) + __popcll(cmB);
            if (ncoll != 0 && ncoll != PP) {          // overlap true (wave-uniform)
                liveMask |= (1 << k);
                // 100-bit FREE mask F = fA | fB<<64 ; G = F>>60 (rows 6..9)
                const unsigned long long fA = ~cmA;
                const unsigned long long fB = (~cmB) & ((1ull << 36) - 1ull);
                const unsigned long long G  = (fA >> 60) | (fB << 4);
                {   // slot A: nearest free column in own row iA
                    const unsigned loA = (unsigned)(fA >> shA);
                    const unsigned gA  = (unsigned)(G  >> sGA);
                    const unsigned m10 = ((iA < 6) ? loA : gA) & 0x3FFu;
                    const unsigned tt  = (m10 >> jA) | (__brev(m10) >> rshA) | MARK;
                    const float d  = (float)__builtin_ctz(tt);
                    const float ds = d * sy;
                    s_w[wvu][k][lane] = ds * ds;
                }
                if (hasB) {  // slot B: row iB >= 6, always via G
                    const unsigned m10 = ((unsigned)(G >> sGB)) & 0x3FFu;
                    const unsigned tt  = (m10 >> jB) | (__brev(m10) >> rshB) | MARK;
                    const float d  = (float)__builtin_ctz(tt);
                    const float ds = d * sy;
                    s_w[wvu][k][lane + 64] = ds * ds;
                }
            }
        }
    }
    // ONE drain for all tables (same-wave write->read ordering)
    asm volatile("s_waitcnt lgkmcnt(0)" ::: "memory");
    __builtin_amdgcn_wave_barrier();

    // ---- phase 2b: min over rows via table reads + loss ----
    float acc = 0.0f;
    #pragma unroll
    for (int k = 0; k < 4; ++k) {
        if ((liveMask >> k) & 1) {                 // wave-uniform
            const float* wt = &s_w[wvu][k][0];
            float mA = 1e30f, mB = 1e30f;
            #pragma unroll
            for (int r = 0; r < 10; r += 2) {
                const float wA0 = wt[r * 10 + jA];
                const float wA1 = wt[r * 10 + 10 + jA];
                mA = fminf(mA, fminf(di2A[r] + wA0, di2A[r + 1] + wA1));
                const float wB0 = wt[r * 10 + jB];
                const float wB1 = wt[r * 10 + 10 + jB];
                mB = fminf(mB, fminf(di2B[r] + wB0, di2B[r + 1] + wB1));
            }
            acc += (vA[k] == 0.0f) ? (1.0f - sqrtf(mA) * inv_diag) : 0.0f;
            acc += (vB[k] == 0.0f) ? (1.0f - sqrtf(mB) * inv_diag) : 0.0f;
        }
    }

    // ---- wave reduce -> LDS -> block reduce -> single store ----
    #pragma unroll
    for (int off = 32; off > 0; off >>= 1) acc += __shfl_down(acc, off);
    if (lane == 0) s_part[wvu] = acc;
    __syncthreads();
    if (threadIdx.x < 64) {
        float v = (lane < NWAVE) ? s_part[lane] : 0.0f;
        v += __shfl_down(v, 8);
        v += __shfl_down(v, 4);
        v += __shfl_down(v, 2);
        v += __shfl_down(v, 1);
        if (lane == 0) out[bn] = v;   // every output written -> no memset needed
    }
}

extern "C" void kernel_launch(void* const* d_in, const int* in_sizes, int n_in,
                              void* d_out, int out_size, void* d_ws, size_t ws_size,
                              hipStream_t stream) {
    const float* x      = (const float*)d_in[0];
    const float* dmap   = (const float*)d_in[1];
    const float* extent = (const float*)d_in[2];
    const float* rfa    = (const float*)d_in[3];
    float* out = (float*)d_out;

    mapcoll_fused<<<BB * NN, NWAVE * 64, 0, stream>>>(x, dmap, extent, rfa, out);
}

// Round 16
// 10.998 us; speedup vs baseline: 1.0102x; 1.0102x over previous
//
#include <hip/hip_runtime.h>
#include <math.h>

// Problem constants from the reference
#define BB 32
#define NN 8
#define TT 52
#define HH 224
#define WW 224
#define PP 100    // 10x10 local grid; point p: slot A = lane p (p<64), slot B = lane p-64
#define NWAVE 16  // waves per block (1024 threads); block = one (b,n) output

__device__ __forceinline__ float rlane_f(float v, int l) {
    return __int_as_float(__builtin_amdgcn_readlane(__float_as_int(v), l));
}

__global__ __launch_bounds__(NWAVE * 64) void mapcoll_fused(
    const float* __restrict__ x,        // (B,N,T,6)
    const float* __restrict__ dmap,     // (B,H,W)
    const float* __restrict__ extent,   // (B,3)
    const float* __restrict__ rfa,      // (B,3,3)
    float* __restrict__ out)            // (B*N)
{
    const int bn   = blockIdx.x;        // 0..255
    const int b    = bn >> 3;           // NN == 8
    const int lane = threadIdx.x & 63;
    const int wvu  = __builtin_amdgcn_readfirstlane((int)(threadIdx.x >> 6));

    __shared__ float s_w[NWAVE][4][128];   // per-wave per-t dj^2*sy^2 table, idx = r*10+j
    __shared__ float s_part[NWAVE];

    // ---- per-b uniforms (scalar loads) ----
    const float lwx = extent[b * 3 + 0];
    const float lwy = extent[b * 3 + 1];
    const float inv_diag = 1.0f / sqrtf(lwx * lwx + lwy * lwy);
    const float r00 = rfa[b*9+0], r01 = rfa[b*9+1], r02 = rfa[b*9+2];
    const float r10 = rfa[b*9+3], r11 = rfa[b*9+4], r12 = rfa[b*9+5];
    const float* __restrict__ map_b = dmap + (size_t)b * (HH * WW);
    // Rigid-motion invariance: |a_p - a_q|^2 = ((i_p-i_q)*sx)^2 + ((j_p-j_q)*sy)^2
    const float sx  = lwx * (1.0f / 9.0f);
    const float sy  = lwy * (1.0f / 9.0f);

    // ---- lane-parallel prologue: lane t<52 builds fused transform uniforms ----
    // fx = p0*u00 + p1*u01 + u0c ; fy = p0*u10 + p1*u11 + u1c   (per-t uniforms)
    float u00 = 0.f, u01 = 0.f, u0c = 0.f, u10 = 0.f, u11 = 0.f, u1c = 0.f;
    if (lane < TT) {
        const int base = (bn * TT + lane) * 6;
        const float2 p2 = *reinterpret_cast<const float2*>(x + base);
        const float yw = x[base + 3];
        const float sn = __sinf(yw), cs = __cosf(yw);
        u00 = cs * r00 + sn * r01;
        u01 = cs * r01 - sn * r00;
        u0c = p2.x * r00 + p2.y * r01 + r02;
        u10 = cs * r10 + sn * r11;
        u11 = cs * r11 - sn * r10;
        u1c = p2.x * r10 + p2.y * r11 + r12;
    }

    // ---- per-lane geometry (t-invariant); B slot defined for ALL lanes ----
    const int iA = lane / 10, jA = lane - iA * 10;
    const int pB = lane + 64;                 // 64..127; only 64..99 are real
    const int iB = pB / 10,   jB = pB - iB * 10;
    const bool hasB = (lane < PP - 64);       // 36 lanes own a real B point
    const float p0A = (-0.5f + (float)iA * (1.0f/9.0f)) * lwx;
    const float p1A = (-0.5f + (float)jA * (1.0f/9.0f)) * lwy;
    const float p0B = (-0.5f + (float)iB * (1.0f/9.0f)) * lwx;   // garbage lanes>=36: finite
    const float p1B = (-0.5f + (float)jB * (1.0f/9.0f)) * lwy;
    const unsigned long long validB = (1ull << 36) - 1ull;

    // scan shift constants (per-lane, t-invariant)
    const int shA  = (10 * iA) & 63;                           // into fA (iA<6)
    const int sGA  = (10 * iA - 60) < 0 ? 0 : (10 * iA - 60);  // into G (iA>=6)
    const int sGB  = ((10 * iB - 60) & 63);                    // B always via G (iB>=6)
    const int rshA = 31 - jA;                                  // brev fold shift
    const int rshB = 31 - jB;

    // di^2 tables (hoisted out of the t loop)
    float di2A[10], di2B[10];
    #pragma unroll
    for (int r = 0; r < 10; ++r) {
        const float dA = (float)(iA - r) * sx; di2A[r] = dA * dA;
        const float dB = (float)(iB - r) * sx; di2B[r] = dB * dB;
    }

    const unsigned MARK = 1u << 25;   // empty-row sentinel: d=25 -> 625*sy2 > 26.9 max

    // t distribution: waves 0..3 -> 4 t's, waves 4..15 -> 3 t's (52 total)
    const int kn = (wvu < 4) ? 4 : 3;
    const int t0 = (wvu < 4) ? (wvu * 4) : (16 + (wvu - 4) * 3);

    // ---- phase 1: transforms + rasterize + issue ALL gathers (branch-free) ----
    float vA[4], vB[4];
    #pragma unroll
    for (int k = 0; k < 4; ++k) {
        vA[k] = 1.0f;                       // "free" for skipped slots
        vB[k] = 1.0f;
        if (k < kn) {                       // wave-uniform guard
            const int t = t0 + k;
            const float a00 = rlane_f(u00, t), a01 = rlane_f(u01, t), a0c = rlane_f(u0c, t);
            const float a10 = rlane_f(u10, t), a11 = rlane_f(u11, t), a1c = rlane_f(u1c, t);
            {
                const float fx = fmaf(p0A, a00, fmaf(p1A, a01, a0c));
                const float fy = fmaf(p0A, a10, fmaf(p1A, a11, a1c));
                int ix = (int)fx, iy = (int)fy;   // trunc cast, then clip (ref semantics)
                ix = ix < 0 ? 0 : (ix > WW - 1 ? WW - 1 : ix);
                iy = iy < 0 ? 0 : (iy > HH - 1 ? HH - 1 : iy);
                vA[k] = map_b[iy * WW + ix];
            }
            {   // ALL 64 lanes gather slot B; clamped addresses are always safe
                const float fx = fmaf(p0B, a00, fmaf(p1B, a01, a0c));
                const float fy = fmaf(p0B, a10, fmaf(p1B, a11, a1c));
                int ix = (int)fx, iy = (int)fy;
                ix = ix < 0 ? 0 : (ix > WW - 1 ? WW - 1 : ix);
                iy = iy < 0 ? 0 : (iy > HH - 1 ? HH - 1 : iy);
                vB[k] = map_b[iy * WW + ix];
            }
        }
    }

    // ---- phase 2a: ballots + mask build + per-lane scans + LDS table writes ----
    int liveMask = 0;                       // wave-uniform
    #pragma unroll
    for (int k = 0; k < 4; ++k) {
        if (k < kn) {
            const int clA = (vA[k] == 0.0f) ? 1 : 0;  // offroad==1 <=> drv==0 ({0,1} map)
            const int clB = (vB[k] == 0.0f) ? 1 : 0;
            const unsigned long long cmA = __ballot(clA);
            const unsigned long long cmB = __ballot(clB) & validB;   // mask garbage lanes
            const int ncoll = __popcll(cmA) + __popcll(cmB);
            if (ncoll != 0 && ncoll != PP) {          // overlap true (wave-uniform)
                liveMask |= (1 << k);
                // 100-bit FREE mask F = fA | fB<<64 ; G = F>>60 (rows 6..9)
                const unsigned long long fA = ~cmA;
                const unsigned long long fB = (~cmB) & validB;
                const unsigned long long G  = (fA >> 60) | (fB << 4);
                {   // slot A: nearest free column in own row iA
                    const unsigned loA = (unsigned)(fA >> shA);
                    const unsigned gA  = (unsigned)(G  >> sGA);
                    const unsigned m10 = ((iA < 6) ? loA : gA) & 0x3FFu;
                    const unsigned tt  = (m10 >> jA) | (__brev(m10) >> rshA) | MARK;
                    const float d  = (float)__builtin_ctz(tt);
                    const float ds = d * sy;
                    s_w[wvu][k][lane] = ds * ds;
                }
                {   // slot B, branch-free: lanes>=36 write pad region [100..127]
                    const unsigned m10 = ((unsigned)(G >> sGB)) & 0x3FFu;
                    const unsigned tt  = (m10 >> jB) | (__brev(m10) >> rshB) | MARK;
                    const float d  = (float)__builtin_ctz(tt);
                    const float ds = d * sy;
                    s_w[wvu][k][lane + 64] = ds * ds;   // idx <= 127, pad never read
                }
            }
        }
    }
    // ONE drain for all tables (same-wave write->read ordering)
    asm volatile("s_waitcnt lgkmcnt(0)" ::: "memory");
    __builtin_amdgcn_wave_barrier();

    // ---- phase 2b: min over rows via table reads + loss ----
    float acc = 0.0f;
    #pragma unroll
    for (int k = 0; k < 4; ++k) {
        if ((liveMask >> k) & 1) {                 // wave-uniform
            const float* wt = &s_w[wvu][k][0];
            float mA = 1e30f, mB = 1e30f;
            #pragma unroll
            for (int r = 0; r < 10; r += 2) {
                const float wA0 = wt[r * 10 + jA];
                const float wA1 = wt[r * 10 + 10 + jA];
                mA = fminf(mA, fminf(di2A[r] + wA0, di2A[r + 1] + wA1));
                const float wB0 = wt[r * 10 + jB];
                const float wB1 = wt[r * 10 + 10 + jB];
                mB = fminf(mB, fminf(di2B[r] + wB0, di2B[r + 1] + wB1));
            }
            acc += (vA[k] == 0.0f) ? (1.0f - sqrtf(mA) * inv_diag) : 0.0f;
            // R15 bug fix: garbage lanes (>=36) gathered real pixels; their
            // loss must be masked out (ballot was masked, accumulate wasn't).
            acc += (hasB && vB[k] == 0.0f) ? (1.0f - sqrtf(mB) * inv_diag) : 0.0f;
        }
    }

    // ---- wave reduce -> LDS -> block reduce -> single store ----
    #pragma unroll
    for (int off = 32; off > 0; off >>= 1) acc += __shfl_down(acc, off);
    if (lane == 0) s_part[wvu] = acc;
    __syncthreads();
    if (threadIdx.x < 64) {
        float v = (lane < NWAVE) ? s_part[lane] : 0.0f;
        v += __shfl_down(v, 8);
        v += __shfl_down(v, 4);
        v += __shfl_down(v, 2);
        v += __shfl_down(v, 1);
        if (lane == 0) out[bn] = v;   // every output written -> no memset needed
    }
}

extern "C" void kernel_launch(void* const* d_in, const int* in_sizes, int n_in,
                              void* d_out, int out_size, void* d_ws, size_t ws_size,
                              hipStream_t stream) {
    const float* x      = (const float*)d_in[0];
    const float* dmap   = (const float*)d_in[1];
    const float* extent = (const float*)d_in[2];
    const float* rfa    = (const float*)d_in[3];
    float* out = (float*)d_out;

    mapcoll_fused<<<BB * NN, NWAVE * 64, 0, stream>>>(x, dmap, extent, rfa, out);
}